// Round 1
// baseline (430.350 us; speedup 1.0000x reference)
//
#include <hip/hip_runtime.h>
#include <math.h>

#ifndef N_POINTS_BLOCK
#define N_POINTS_BLOCK 256
#endif

static constexpr float kSceneScale = 4.0f;

__device__ __forceinline__ void fma4(float4& acc, float w, const float4& c) {
    acc.x = fmaf(w, c.x, acc.x);
    acc.y = fmaf(w, c.y, acc.y);
    acc.z = fmaf(w, c.z, acc.z);
    acc.w = fmaf(w, c.w, acc.w);
}

template <int RES>
__device__ __forceinline__ void trilerp_acc(const float4* __restrict__ cb,
                                            float x, float y, float z,
                                            float4& acc) {
    const float s = (float)(RES - 1);
    float fx = x * s;
    float fy = y * s;
    float fz = z * s;
    // pos >= 0 (x,y,z clamped to [0,1]) so (int) == floor
    int x0 = min((int)fx, RES - 2);
    int y0 = min((int)fy, RES - 2);
    int z0 = min((int)fz, RES - 2);
    float tx = fx - (float)x0;
    float ty = fy - (float)y0;
    float tz = fz - (float)z0;

    int base = (x0 * RES + y0) * RES + z0;   // row-major x*RES^2 + y*RES + z

    // z-pairs are contiguous 32B; issue all 8 loads up front for MLP.
    float4 c000 = cb[base];
    float4 c001 = cb[base + 1];
    float4 c010 = cb[base + RES];
    float4 c011 = cb[base + RES + 1];
    float4 c100 = cb[base + RES * RES];
    float4 c101 = cb[base + RES * RES + 1];
    float4 c110 = cb[base + RES * RES + RES];
    float4 c111 = cb[base + RES * RES + RES + 1];

    float wx0 = 1.0f - tx, wx1 = tx;
    float wy0 = 1.0f - ty, wy1 = ty;
    float wz0 = 1.0f - tz, wz1 = tz;

    fma4(acc, wx0 * wy0 * wz0, c000);
    fma4(acc, wx0 * wy0 * wz1, c001);
    fma4(acc, wx0 * wy1 * wz0, c010);
    fma4(acc, wx0 * wy1 * wz1, c011);
    fma4(acc, wx1 * wy0 * wz0, c100);
    fma4(acc, wx1 * wy0 * wz1, c101);
    fma4(acc, wx1 * wy1 * wz0, c110);
    fma4(acc, wx1 * wy1 * wz1, c111);
}

__global__ __launch_bounds__(N_POINTS_BLOCK) void plenoxels_kernel(
        const float* __restrict__ pts,
        const float4* __restrict__ cb0,
        const float4* __restrict__ cb1,
        const float4* __restrict__ cb2,
        const float4* __restrict__ cb3,
        const float4* __restrict__ cb4,
        float* __restrict__ out,
        int n) {
    int i = blockIdx.x * blockDim.x + threadIdx.x;
    if (i >= n) return;

    float px = pts[3 * i + 0] * (1.0f / kSceneScale);
    float py = pts[3 * i + 1] * (1.0f / kSceneScale);
    float pz = pts[3 * i + 2] * (1.0f / kSceneScale);

    bool inside = (fabsf(px) < 0.5f) && (fabsf(py) < 0.5f) && (fabsf(pz) < 0.5f);

    float x = fminf(fmaxf(px + 0.5f, 0.0f), 1.0f);
    float y = fminf(fmaxf(py + 0.5f, 0.0f), 1.0f);
    float z = fminf(fmaxf(pz + 0.5f, 0.0f), 1.0f);

    float4 acc = make_float4(0.0f, 0.0f, 0.0f, 0.0f);
    trilerp_acc<16>(cb0, x, y, z, acc);
    trilerp_acc<32>(cb1, x, y, z, acc);
    trilerp_acc<64>(cb2, x, y, z, acc);
    trilerp_acc<128>(cb3, x, y, z, acc);
    trilerp_acc<256>(cb4, x, y, z, acc);

    // Output: color (N,3) flat, then sigma (N,1).
    float c0 = inside ? acc.x : 0.0f;
    float c1 = inside ? acc.y : 0.0f;
    float c2 = inside ? acc.z : 0.0f;
    float sg = inside ? expf(acc.w) : 0.0f;   // exp(-1e5) underflows to 0 in ref

    out[3 * i + 0] = c0;
    out[3 * i + 1] = c1;
    out[3 * i + 2] = c2;
    out[(size_t)3 * n + i] = sg;
}

extern "C" void kernel_launch(void* const* d_in, const int* in_sizes, int n_in,
                              void* d_out, int out_size, void* d_ws, size_t ws_size,
                              hipStream_t stream) {
    const float* pts = (const float*)d_in[0];
    // d_in[1] is `d` (directions) — unused by the reference computation.
    const float4* cb0 = (const float4*)d_in[2];
    const float4* cb1 = (const float4*)d_in[3];
    const float4* cb2 = (const float4*)d_in[4];
    const float4* cb3 = (const float4*)d_in[5];
    const float4* cb4 = (const float4*)d_in[6];
    float* out = (float*)d_out;

    int n = in_sizes[0] / 3;   // pts is (N,3)

    dim3 block(N_POINTS_BLOCK);
    dim3 grid((n + N_POINTS_BLOCK - 1) / N_POINTS_BLOCK);
    plenoxels_kernel<<<grid, block, 0, stream>>>(pts, cb0, cb1, cb2, cb3, cb4, out, n);
}